// Round 8
// baseline (269.519 us; speedup 1.0000x reference)
//
#include <hip/hip_runtime.h>

// MaskUnitAttention fused kernel, MI355X gfx950.
// B=64, N=3136 (=64 tokens * 49 windows, window-fastest), DIM=96, DIM_OUT=192,
// HEADS=2, HEAD_DIM=96, Q_STRIDE=4, WINDOW_SIZE=16.
// v8: LAUNCH-RATE FIX. v4/v7 measured dur ≈ 3136 blocks / ~36.5 WG/us with
// residency (2.2 blocks/CU) far under every cap -> the kernel is workgroup-
// dispatch-bound. v8 keeps the v7 block verbatim but processes 2 consecutive
// windows per block (grid 1568): launch floor halves (~43us), residency rises
// to its equilibrium (~4.3 blocks/CU, LDS cap 5). Loop seam needs no extra
// barrier: it1 staging writes region1 only; it0 laggards only touch o_s
// (disjoint); v_s reads fenced by B5; qp writes ordered via B2-it1.
// v7 carried forward: 31.2KB LDS, S^T operand-swap softmax (P in regs),
// K/V swizzled stores, rotating weight buffers, (256,2).

#define NW 49
#define NTOK 3136
#define DIM 96
#define DOUT 192

// ws layout (u16 element offsets)
#define WSQ 0
#define WSBQ 55296
#define WSP 55872
#define WSBP 92736
#define WSTOT 92928

typedef __bf16 bf16x8 __attribute__((ext_vector_type(8)));
typedef float f32x4 __attribute__((ext_vector_type(4)));
typedef unsigned short u16x8 __attribute__((ext_vector_type(8)));
typedef unsigned short u16x4 __attribute__((ext_vector_type(4)));
typedef unsigned int   u32x4 __attribute__((ext_vector_type(4)));

__device__ __forceinline__ unsigned short f2bf(float f) {
    return __builtin_bit_cast(unsigned short, (__bf16)f);   // RNE
}
__device__ __forceinline__ float bf2f(unsigned short h) {
    unsigned int u = ((unsigned int)h) << 16;
    return __builtin_bit_cast(float, u);
}

// Data sniff: x ~ N(0,1). bf16 data -> even-indexed u16s all have sane exponents.
// fp32 data -> even-indexed u16s are mantissa low-halves (uniform) -> ~16% sane.
__device__ __forceinline__ bool sniff_fp32(const unsigned short* x16) {
    int sane = 0;
    #pragma unroll
    for (int i = 0; i < 32; ++i) {
        unsigned e = ((unsigned)x16[2 * i] >> 7) & 0xFFu;
        sane += (e >= 100u && e <= 141u) ? 1 : 0;   // |v| in [2^-27, 2^14]
    }
    return sane < 24;
}

__device__ __forceinline__ bf16x8 ldb(const unsigned short* p) {
    return __builtin_bit_cast(bf16x8, *(const u16x8*)p);
}

// ---- pre-kernel: weights/biases -> bf16 in workspace (runs once, ~186 KB) ----
__global__ __launch_bounds__(256)
void conv_weights(const void* __restrict__ x,
                  const void* __restrict__ w_qkv, const void* __restrict__ b_qkv,
                  const void* __restrict__ w_proj, const void* __restrict__ b_proj,
                  unsigned short* __restrict__ ws)
{
    const bool f32m = sniff_fp32((const unsigned short*)x);
    int t = blockIdx.x * 256 + threadIdx.x;
    if (t >= WSTOT / 8) return;
    int off = t * 8;
    const void* src;
    int rel;
    if (off < WSBQ)      { src = w_qkv;  rel = off; }
    else if (off < WSP)  { src = b_qkv;  rel = off - WSBQ; }
    else if (off < WSBP) { src = w_proj; rel = off - WSP; }
    else                 { src = b_proj; rel = off - WSBP; }
    u16x8 v;
    if (f32m) {
        const float* p = (const float*)src + rel;
        f32x4 a = *(const f32x4*)p;
        f32x4 bb = *(const f32x4*)(p + 4);
        v[0] = f2bf(a[0]);  v[1] = f2bf(a[1]);  v[2] = f2bf(a[2]);  v[3] = f2bf(a[3]);
        v[4] = f2bf(bb[0]); v[5] = f2bf(bb[1]); v[6] = f2bf(bb[2]); v[7] = f2bf(bb[3]);
    } else {
        v = *(const u16x8*)((const unsigned short*)src + rel);
    }
    *(u16x8*)(ws + off) = v;
}

// ---- main fused kernel: one block per 2 consecutive (b, window) pairs ----
__global__ __launch_bounds__(256, 2)
void mua_main(const void* __restrict__ x,
              const unsigned short* __restrict__ ws,
              void* __restrict__ out)
{
    const int bid = blockIdx.x;
    const int tid  = threadIdx.x;
    const int wave = tid >> 6;
    const int lane = tid & 63;
    const int quad = lane >> 4;
    const int l16  = lane & 15;

    // 31232 B LDS -> 5 blocks/CU cap. Region 1 (u16 [0,12288)) time-shared:
    //   x_s [64][104]              (dead after B2)
    //   k_s [2][64][96] swizzled   (written after B2, dead after B4)
    //   v_s [2][96][64] swizzled   (written after B4)
    // qp_s [2][16][104] @12288 (o_s [16][200]=3200 aliases; qp dead after qa reads)
    __shared__ __attribute__((aligned(16))) unsigned short lds[15616];
    unsigned short* x_s  = lds;
    unsigned short* k_s  = lds;
    unsigned short* v_s  = lds;
    unsigned short* qp_s = lds + 12288;
    unsigned short* o_s  = lds + 12288;

    const bool f32m = sniff_fp32((const unsigned short*)x);
    const int h   = wave >> 1;
    const int sub = wave & 1;

    #pragma unroll 1
    for (int it = 0; it < 2; ++it) {
        const int win = bid * 2 + it;
        const int b   = win / NW;
        const int wi  = win - b * NW;

        // ---- preload wq tiles 0..2 (3-deep rotation, 36 regs) + all biases ----
        // Tile tt = nt*4 + wave: nt 0..2 -> q tiles (0..11), nt 3..5 -> k (12..23).
        bf16x8 wq[3][3];
        float  biasq[6];
        #pragma unroll
        for (int nt = 0; nt < 3; ++nt) {
            const int c = (nt * 4 + wave) * 16 + l16;
            #pragma unroll
            for (int ks = 0; ks < 3; ++ks)
                wq[nt][ks] = ldb(ws + WSQ + c * 96 + ks * 32 + quad * 8);
        }
        #pragma unroll
        for (int nt = 0; nt < 6; ++nt)
            biasq[nt] = bf2f(ws[WSBQ + (nt * 4 + wave) * 16 + l16]);

        // ---- phase 1: stage x tile (64 rows x 96, rows strided by 49*96) ----
        {
            const size_t xoff = ((size_t)b * NTOK + wi) * DIM;
            if (f32m) {
                #pragma unroll
                for (int i = 0; i < 3; ++i) {
                    int chunk = tid + i * 256;          // 768 = 64 rows * 12 chunks
                    int row = chunk / 12;
                    int c16 = chunk - row * 12;
                    const float* p = (const float*)x + xoff + (size_t)row * (NW * DIM) + c16 * 8;
                    f32x4 a = *(const f32x4*)p;
                    f32x4 bb = *(const f32x4*)(p + 4);
                    u16x8 r;
                    r[0] = f2bf(a[0]);  r[1] = f2bf(a[1]);  r[2] = f2bf(a[2]);  r[3] = f2bf(a[3]);
                    r[4] = f2bf(bb[0]); r[5] = f2bf(bb[1]); r[6] = f2bf(bb[2]); r[7] = f2bf(bb[3]);
                    *(u16x8*)&x_s[row * 104 + c16 * 8] = r;
                }
            } else {
                #pragma unroll
                for (int i = 0; i < 3; ++i) {
                    int chunk = tid + i * 256;
                    int row = chunk / 12;
                    int c16 = chunk - row * 12;
                    const unsigned short* p = (const unsigned short*)x + xoff + (size_t)row * (NW * DIM) + c16 * 8;
                    *(u16x8*)&x_s[row * 104 + c16 * 8] = *(const u16x8*)p;
                }
            }
        }
        __syncthreads();   // B1: x staged (also drains preloaded wq tiles)

        // ---- phase 2: A-fragments of x into registers (live until v-GEMM) ----
        bf16x8 afr[4][3];
        #pragma unroll
        for (int mt = 0; mt < 4; ++mt)
            #pragma unroll
            for (int ks = 0; ks < 3; ++ks)
                afr[mt][ks] = ldb(&x_s[(mt * 16 + l16) * 104 + ks * 32 + quad * 8]);
        __syncthreads();   // B2: x region free -> k may overwrite

        // ---- phase 3a: q+k channels; wq slot nt%3 refilled with tile nt+3 ----
        #pragma unroll
        for (int nt = 0; nt < 6; ++nt) {
            const int slot = nt % 3;   // compile-time after unroll
            f32x4 acc[4];
            #pragma unroll
            for (int mt = 0; mt < 4; ++mt) {
                acc[mt] = (f32x4){0.f, 0.f, 0.f, 0.f};
                #pragma unroll
                for (int ks = 0; ks < 3; ++ks)
                    acc[mt] = __builtin_amdgcn_mfma_f32_16x16x32_bf16(afr[mt][ks], wq[slot][ks], acc[mt], 0, 0, 0);
            }
            if (nt < 3) {   // refill slot with tile nt+3 (WAR on slot orders after MFMAs)
                const int c2 = ((nt + 3) * 4 + wave) * 16 + l16;
                #pragma unroll
                for (int ks = 0; ks < 3; ++ks)
                    wq[slot][ks] = ldb(ws + WSQ + c2 * 96 + ks * 32 + quad * 8);
            }
            // C-layout: col(channel) = l16, row(token) = quad*4 + r (+ mt*16)
            const int tt = nt * 4 + wave;
            const float bias = biasq[nt];
            if (nt < 3) {
                // q tiles: maxpool over the 4 M-tiles (pool groups are exactly mt)
                const int hd = tt / 6;
                const int d  = (tt % 6) * 16 + l16;
                #pragma unroll
                for (int r = 0; r < 4; ++r) {
                    float m = fmaxf(fmaxf(acc[0][r], acc[1][r]), fmaxf(acc[2][r], acc[3][r])) + bias;
                    qp_s[(hd * 16 + quad * 4 + r) * 104 + d] = f2bf(m);
                }
            } else {
                // K swizzled: col = ((d>>3)^(row&3))*8 + (d&7); row&3 == r here.
                const int tk = tt - 12;
                const int hd = tk / 6;
                const int dbh  = ((tk % 6) * 16) / 8 + (l16 >> 3);   // d>>3
                const int dlow = l16 & 7;
                #pragma unroll
                for (int mt = 0; mt < 4; ++mt)
                    #pragma unroll
                    for (int r = 0; r < 4; ++r)
                        k_s[hd * 6144 + (mt * 16 + quad * 4 + r) * 96 + ((dbh ^ r) << 3) + dlow]
                            = f2bf(acc[mt][r] + bias);
            }
        }
        __syncthreads();   // B3: qp/k ready

        // ---- phase 4: S^T = K @ qp^T (operand swap), per-lane softmax, P -> regs ----
        bf16x8 qa[3];
        #pragma unroll
        for (int ks = 0; ks < 3; ++ks)
            qa[ks] = ldb(&qp_s[(h * 16 + l16) * 104 + ks * 32 + quad * 8]);
        // st[mt] C-layout: row = key (mt*16 + quad*4 + r), col = qrow (l16)
        f32x4 st[4];
        #pragma unroll
        for (int mt = 0; mt < 4; ++mt) st[mt] = (f32x4){0.f, 0.f, 0.f, 0.f};
        #pragma unroll
        for (int ks = 0; ks < 3; ++ks)
            #pragma unroll
            for (int mt = 0; mt < 4; ++mt) {
                bf16x8 kb = ldb(&k_s[h * 6144 + (mt * 16 + l16) * 96 + (((ks * 4 + quad) ^ (l16 & 3)) << 3)]);
                st[mt] = __builtin_amdgcn_mfma_f32_16x16x32_bf16(kb, qa[ks], st[mt], 0, 0, 0);
            }
        // softmax over the 16 per-lane values (all for qrow = l16) + cross-quad reduce
        const float cexp = 0.10206207261596576f * 1.4426950408889634f;  // 96^-0.5 * log2e
        float mx;
        {
            float m0 = fmaxf(fmaxf(st[0][0], st[0][1]), fmaxf(st[0][2], st[0][3]));
            float m1 = fmaxf(fmaxf(st[1][0], st[1][1]), fmaxf(st[1][2], st[1][3]));
            float m2 = fmaxf(fmaxf(st[2][0], st[2][1]), fmaxf(st[2][2], st[2][3]));
            float m3 = fmaxf(fmaxf(st[3][0], st[3][1]), fmaxf(st[3][2], st[3][3]));
            mx = fmaxf(fmaxf(m0, m1), fmaxf(m2, m3));
        }
        mx = fmaxf(mx, __shfl_xor(mx, 16));
        mx = fmaxf(mx, __shfl_xor(mx, 32));
        float e[4][4];
        #pragma unroll
        for (int mt = 0; mt < 4; ++mt)
            #pragma unroll
            for (int r = 0; r < 4; ++r)
                e[mt][r] = exp2f((st[mt][r] - mx) * cexp);
        float sum;
        {
            float s0 = (e[0][0] + e[0][1]) + (e[0][2] + e[0][3]);
            float s1 = (e[1][0] + e[1][1]) + (e[1][2] + e[1][3]);
            float s2 = (e[2][0] + e[2][1]) + (e[2][2] + e[2][3]);
            float s3 = (e[3][0] + e[3][1]) + (e[3][2] + e[3][3]);
            sum = (s0 + s1) + (s2 + s3);
        }
        sum += __shfl_xor(sum, 16);
        sum += __shfl_xor(sum, 32);
        const float rinv_l = 1.0f / sum;
        // redistribute rinv to O-epilogue layout (qrow = quad*4 + r)
        float rs[4];
        #pragma unroll
        for (int r = 0; r < 4; ++r)
            rs[r] = __shfl(rinv_l, (lane & 48) + quad * 4 + r);
        // assemble PV A-fragments in-register: pa[ks2] = P[qrow=l16][ks2*32+quad*8 ..+8]
        unsigned wlo[4], whi[4];
        #pragma unroll
        for (int mt = 0; mt < 4; ++mt) {
            wlo[mt] = (unsigned)f2bf(e[mt][0]) | ((unsigned)f2bf(e[mt][1]) << 16);
            whi[mt] = (unsigned)f2bf(e[mt][2]) | ((unsigned)f2bf(e[mt][3]) << 16);
        }
        bf16x8 pa[2];
        {
            const int srcA = ((quad & 1) * 2) * 16 + l16;   // first source quad-lane
            const int srcB = srcA + 16;                     // second source quad-lane
            const bool hiT = quad >= 2;                     // receiver tile = 2*ks2 + (quad>>1)
            #pragma unroll
            for (int ks2 = 0; ks2 < 2; ++ks2) {
                unsigned lo0a = __shfl(wlo[2 * ks2], srcA), lo0b = __shfl(wlo[2 * ks2 + 1], srcA);
                unsigned hi0a = __shfl(whi[2 * ks2], srcA), hi0b = __shfl(whi[2 * ks2 + 1], srcA);
                unsigned lo1a = __shfl(wlo[2 * ks2], srcB), lo1b = __shfl(wlo[2 * ks2 + 1], srcB);
                unsigned hi1a = __shfl(whi[2 * ks2], srcB), hi1b = __shfl(whi[2 * ks2 + 1], srcB);
                u32x4 W;
                W[0] = hiT ? lo0b : lo0a;
                W[1] = hiT ? hi0b : hi0a;
                W[2] = hiT ? lo1b : lo1a;
                W[3] = hiT ? hi1b : hi1a;
                pa[ks2] = __builtin_bit_cast(bf16x8, W);
            }
        }

        // ---- preload v-weight tiles 0,1 (2-deep rotation); hide under B4 wait ----
        bf16x8 wv[2][3];
        float  biasv[3];
        #pragma unroll
        for (int i = 0; i < 2; ++i) {
            const int c = 384 + (i * 4 + wave) * 16 + l16;
            #pragma unroll
            for (int ks = 0; ks < 3; ++ks)
                wv[i][ks] = ldb(ws + WSQ + c * 96 + ks * 32 + quad * 8);
        }
        #pragma unroll
        for (int i = 0; i < 3; ++i)
            biasv[i] = bf2f(ws[WSBQ + 384 + (i * 4 + wave) * 16 + l16]);
        __syncthreads();   // B4: all k reads done -> v may overwrite region 1

        // ---- phase 3b: v channels (afr still in regs); v swizzled [head][d][t] ----
        #pragma unroll
        for (int i = 0; i < 3; ++i) {
            const int slot = i & 1;   // compile-time after unroll
            f32x4 acc[4];
            #pragma unroll
            for (int mt = 0; mt < 4; ++mt) {
                acc[mt] = (f32x4){0.f, 0.f, 0.f, 0.f};
                #pragma unroll
                for (int ks = 0; ks < 3; ++ks)
                    acc[mt] = __builtin_amdgcn_mfma_f32_16x16x32_bf16(afr[mt][ks], wv[slot][ks], acc[mt], 0, 0, 0);
            }
            if (i == 0) {   // refill slot 0 with tile 2
                const int c2 = 384 + (2 * 4 + wave) * 16 + l16;
                #pragma unroll
                for (int ks = 0; ks < 3; ++ks)
                    wv[0][ks] = ldb(ws + WSQ + c2 * 96 + ks * 32 + quad * 8);
            }
            const int tv = i * 4 + wave;
            const int hd = tv / 6;
            const int d  = (tv % 6) * 16 + l16;
            const float bias = biasv[i];
            #pragma unroll
            for (int mt = 0; mt < 4; ++mt) {
                u16x4 pk;
                #pragma unroll
                for (int r = 0; r < 4; ++r) pk[r] = f2bf(acc[mt][r] + bias);
                const int tb = 2 * mt + (quad >> 1);     // t-block of t = mt*16 + quad*4
                *(u16x4*)&v_s[hd * 6144 + d * 64 + ((tb ^ (d & 7)) << 3) + (quad & 1) * 4] = pk;
            }
        }

        // ---- hoist proj weights/biases (afr/wv dead); land under B4b + PV ----
        const int cbase = wave * 48;
        bf16x8 wpr[3][6];
        float  biasp[3];
        #pragma unroll
        for (int i = 0; i < 3; ++i) {
            const int c = cbase + i * 16 + l16;
            #pragma unroll
            for (int ks = 0; ks < 6; ++ks)
                wpr[i][ks] = ldb(ws + WSP + c * 192 + ks * 32 + quad * 8);
            biasp[i] = bf2f(ws[WSBP + c]);
        }
        __syncthreads();   // B4b: v ready

        // ---- phase 5: O = P @ V (3 of 6 d-tiles per sub-wave), scale rows ----
        #pragma unroll
        for (int i = 0; i < 3; ++i) {
            const int n0 = (sub * 3 + i) * 16;
            f32x4 oacc = (f32x4){0.f, 0.f, 0.f, 0.f};
            #pragma unroll
            for (int ks2 = 0; ks2 < 2; ++ks2) {
                bf16x8 vb = ldb(&v_s[h * 6144 + (n0 + l16) * 64 + (((ks2 * 4 + quad) ^ (l16 & 7)) << 3)]);
                oacc = __builtin_amdgcn_mfma_f32_16x16x32_bf16(pa[ks2], vb, oacc, 0, 0, 0);
            }
            #pragma unroll
            for (int r = 0; r < 4; ++r)
                o_s[(quad * 4 + r) * 200 + h * 96 + n0 + l16] = f2bf(oacc[r] * rs[r]);
        }
        __syncthreads();   // B5: o ready (also fences v_s reads before next-iter staging)

        // ---- phase 6: out = o @ w_proj^T + b_proj; wave owns 48 channels ----
        bf16x8 oa[6];
        #pragma unroll
        for (int ks = 0; ks < 6; ++ks)
            oa[ks] = ldb(&o_s[l16 * 200 + ks * 32 + quad * 8]);
        #pragma unroll
        for (int i = 0; i < 3; ++i) {
            const int c = cbase + i * 16 + l16;
            f32x4 acc = (f32x4){0.f, 0.f, 0.f, 0.f};
            #pragma unroll
            for (int ks = 0; ks < 6; ++ks)
                acc = __builtin_amdgcn_mfma_f32_16x16x32_bf16(oa[ks], wpr[i][ks], acc, 0, 0, 0);
            const float bias = biasp[i];
            #pragma unroll
            for (int r = 0; r < 4; ++r) {
                const int m = quad * 4 + r;          // out row = b*784 + m*49 + wi
                const size_t idx = ((size_t)(b * 784 + m * NW + wi)) * DOUT + c;
                if (f32m) ((float*)out)[idx] = acc[r] + bias;
                else      ((unsigned short*)out)[idx] = f2bf(acc[r] + bias);
            }
        }
        // Loop seam: it1 staging writes x_s [0,6656) only; any it0 laggard is in
        // phase 6 touching o_s (>=12288) — disjoint. qp writes at it1 happen
        // after B2-it1, which orders them after all it0 phase-6 o_s reads.
    }
}

extern "C" void kernel_launch(void* const* d_in, const int* in_sizes, int n_in,
                              void* d_out, int out_size, void* d_ws, size_t ws_size,
                              hipStream_t stream) {
    const void* x      = d_in[0];
    const void* w_qkv  = d_in[1];
    const void* b_qkv  = d_in[2];
    const void* w_proj = d_in[3];
    const void* b_proj = d_in[4];
    unsigned short* ws = (unsigned short*)d_ws;

    // Pre-kernel: convert weights/biases to bf16 into workspace (stream-ordered).
    dim3 gridc((WSTOT / 8 + 255) / 256), blockc(256);
    hipLaunchKernelGGL(conv_weights, gridc, blockc, 0, stream,
                       x, w_qkv, b_qkv, w_proj, b_proj, ws);

    dim3 grid(NTOK / 2), block(256);   // 1568 blocks x 2 sequential windows
    hipLaunchKernelGGL(mua_main, grid, block, 0, stream, x, ws, d_out);
}

// Round 10
// 196.633 us; speedup vs baseline: 1.3707x; 1.3707x over previous
//
#include <hip/hip_runtime.h>

// MaskUnitAttention fused kernel, MI355X gfx950.
// B=64, N=3136 (=64 tokens * 49 windows, window-fastest), DIM=96, DIM_OUT=192,
// HEADS=2, HEAD_DIM=96, Q_STRIDE=4, WINDOW_SIZE=16.
// v9b: identical to v9 (R8 submission) — that round died to a container/infra
// failure with no measurement (same signature as R3; identical resubmission
// then ran cleanly). Design: SPATIAL WG-HALVING. Launch-rate model (v2/v4/v7:
// dur ≈ N_WG / 36.5us^-1, residency stuck at ~2.2 blocks/CU below all caps)
// says we're WG-dispatch bound. v8's sequential 2-window loop spilled
// (compiler pipelined across the seam into the 128-VGPR cap). v9 halves WG
// count with NO loop: 512-thread blocks = two independent 256-thread halves,
// each running the v7 pipeline verbatim on its own window + own LDS slice
// (2x31232 B = 62464 B < 64KB). Identical barrier schedule in both halves ->
// shared __syncthreads is safe. (512,2) caps VGPR at 256: spill-proof.
// v7 carried: 31.2KB/window LDS, S^T operand-swap softmax (P in regs),
// K/V swizzled stores, rotating weight buffers.

#define NW 49
#define NTOK 3136
#define DIM 96
#define DOUT 192

// ws layout (u16 element offsets)
#define WSQ 0
#define WSBQ 55296
#define WSP 55872
#define WSBP 92736
#define WSTOT 92928

typedef __bf16 bf16x8 __attribute__((ext_vector_type(8)));
typedef float f32x4 __attribute__((ext_vector_type(4)));
typedef unsigned short u16x8 __attribute__((ext_vector_type(8)));
typedef unsigned short u16x4 __attribute__((ext_vector_type(4)));
typedef unsigned int   u32x4 __attribute__((ext_vector_type(4)));

__device__ __forceinline__ unsigned short f2bf(float f) {
    return __builtin_bit_cast(unsigned short, (__bf16)f);   // RNE
}
__device__ __forceinline__ float bf2f(unsigned short h) {
    unsigned int u = ((unsigned int)h) << 16;
    return __builtin_bit_cast(float, u);
}

// Data sniff: x ~ N(0,1). bf16 data -> even-indexed u16s all have sane exponents.
// fp32 data -> even-indexed u16s are mantissa low-halves (uniform) -> ~16% sane.
__device__ __forceinline__ bool sniff_fp32(const unsigned short* x16) {
    int sane = 0;
    #pragma unroll
    for (int i = 0; i < 32; ++i) {
        unsigned e = ((unsigned)x16[2 * i] >> 7) & 0xFFu;
        sane += (e >= 100u && e <= 141u) ? 1 : 0;   // |v| in [2^-27, 2^14]
    }
    return sane < 24;
}

__device__ __forceinline__ bf16x8 ldb(const unsigned short* p) {
    return __builtin_bit_cast(bf16x8, *(const u16x8*)p);
}

// ---- pre-kernel: weights/biases -> bf16 in workspace (runs once, ~186 KB) ----
__global__ __launch_bounds__(256)
void conv_weights(const void* __restrict__ x,
                  const void* __restrict__ w_qkv, const void* __restrict__ b_qkv,
                  const void* __restrict__ w_proj, const void* __restrict__ b_proj,
                  unsigned short* __restrict__ ws)
{
    const bool f32m = sniff_fp32((const unsigned short*)x);
    int t = blockIdx.x * 256 + threadIdx.x;
    if (t >= WSTOT / 8) return;
    int off = t * 8;
    const void* src;
    int rel;
    if (off < WSBQ)      { src = w_qkv;  rel = off; }
    else if (off < WSP)  { src = b_qkv;  rel = off - WSBQ; }
    else if (off < WSBP) { src = w_proj; rel = off - WSP; }
    else                 { src = b_proj; rel = off - WSBP; }
    u16x8 v;
    if (f32m) {
        const float* p = (const float*)src + rel;
        f32x4 a = *(const f32x4*)p;
        f32x4 bb = *(const f32x4*)(p + 4);
        v[0] = f2bf(a[0]);  v[1] = f2bf(a[1]);  v[2] = f2bf(a[2]);  v[3] = f2bf(a[3]);
        v[4] = f2bf(bb[0]); v[5] = f2bf(bb[1]); v[6] = f2bf(bb[2]); v[7] = f2bf(bb[3]);
    } else {
        v = *(const u16x8*)((const unsigned short*)src + rel);
    }
    *(u16x8*)(ws + off) = v;
}

// ---- main fused kernel: 512 threads = 2 independent 256-thread halves,
//      each half owns one (b, window) ----
__global__ __launch_bounds__(512, 2)
void mua_main(const void* __restrict__ x,
              const unsigned short* __restrict__ ws,
              void* __restrict__ out)
{
    const int tid  = threadIdx.x;
    const int half = tid >> 8;          // which window-half of the block
    const int t256 = tid & 255;         // thread id within the half
    const int wave = t256 >> 6;         // 0..3 within half
    const int lane = tid & 63;
    const int quad = lane >> 4;
    const int l16  = lane & 15;
    const int win  = blockIdx.x * 2 + half;
    const int b    = win / NW;
    const int wi   = win - b * NW;

    // Per-half LDS slice: 15616 u16 = 31232 B. Region 1 (u16 [0,12288)):
    //   x_s [64][104]              (dead after B2)
    //   k_s [2][64][96] swizzled   (written after B2, dead after B4)
    //   v_s [2][96][64] swizzled   (written after B4)
    // qp_s [2][16][104] @12288 (o_s [16][200]=3200 aliases; qp dead after qa reads)
    __shared__ __attribute__((aligned(16))) unsigned short lds[31232];
    unsigned short* base = lds + half * 15616;
    unsigned short* x_s  = base;
    unsigned short* k_s  = base;
    unsigned short* v_s  = base;
    unsigned short* qp_s = base + 12288;
    unsigned short* o_s  = base + 12288;

    // ---- preload wq tiles 0..2 (3-deep rotation, 36 regs) + all biases ----
    // Tile tt = nt*4 + wave: nt 0..2 -> q tiles (0..11), nt 3..5 -> k (12..23).
    bf16x8 wq[3][3];
    float  biasq[6];
    #pragma unroll
    for (int nt = 0; nt < 3; ++nt) {
        const int c = (nt * 4 + wave) * 16 + l16;
        #pragma unroll
        for (int ks = 0; ks < 3; ++ks)
            wq[nt][ks] = ldb(ws + WSQ + c * 96 + ks * 32 + quad * 8);
    }
    #pragma unroll
    for (int nt = 0; nt < 6; ++nt)
        biasq[nt] = bf2f(ws[WSBQ + (nt * 4 + wave) * 16 + l16]);

    const bool f32m = sniff_fp32((const unsigned short*)x);

    // ---- phase 1: stage x tile (64 rows x 96, rows strided by 49*96) ----
    {
        const size_t xoff = ((size_t)b * NTOK + wi) * DIM;
        if (f32m) {
            #pragma unroll
            for (int i = 0; i < 3; ++i) {
                int chunk = t256 + i * 256;         // 768 = 64 rows * 12 chunks
                int row = chunk / 12;
                int c16 = chunk - row * 12;
                const float* p = (const float*)x + xoff + (size_t)row * (NW * DIM) + c16 * 8;
                f32x4 a = *(const f32x4*)p;
                f32x4 bb = *(const f32x4*)(p + 4);
                u16x8 r;
                r[0] = f2bf(a[0]);  r[1] = f2bf(a[1]);  r[2] = f2bf(a[2]);  r[3] = f2bf(a[3]);
                r[4] = f2bf(bb[0]); r[5] = f2bf(bb[1]); r[6] = f2bf(bb[2]); r[7] = f2bf(bb[3]);
                *(u16x8*)&x_s[row * 104 + c16 * 8] = r;
            }
        } else {
            #pragma unroll
            for (int i = 0; i < 3; ++i) {
                int chunk = t256 + i * 256;
                int row = chunk / 12;
                int c16 = chunk - row * 12;
                const unsigned short* p = (const unsigned short*)x + xoff + (size_t)row * (NW * DIM) + c16 * 8;
                *(u16x8*)&x_s[row * 104 + c16 * 8] = *(const u16x8*)p;
            }
        }
    }
    __syncthreads();   // B1: x staged (both halves; identical barrier schedule)

    // ---- phase 2: A-fragments of x into registers (live until v-GEMM) ----
    bf16x8 afr[4][3];
    #pragma unroll
    for (int mt = 0; mt < 4; ++mt)
        #pragma unroll
        for (int ks = 0; ks < 3; ++ks)
            afr[mt][ks] = ldb(&x_s[(mt * 16 + l16) * 104 + ks * 32 + quad * 8]);
    __syncthreads();   // B2: x region free -> k may overwrite

    // ---- phase 3a: q+k channels; wq slot nt%3 refilled with tile nt+3 ----
    #pragma unroll
    for (int nt = 0; nt < 6; ++nt) {
        const int slot = nt % 3;   // compile-time after unroll
        f32x4 acc[4];
        #pragma unroll
        for (int mt = 0; mt < 4; ++mt) {
            acc[mt] = (f32x4){0.f, 0.f, 0.f, 0.f};
            #pragma unroll
            for (int ks = 0; ks < 3; ++ks)
                acc[mt] = __builtin_amdgcn_mfma_f32_16x16x32_bf16(afr[mt][ks], wq[slot][ks], acc[mt], 0, 0, 0);
        }
        if (nt < 3) {   // refill slot with tile nt+3 (WAR on slot orders after MFMAs)
            const int c2 = ((nt + 3) * 4 + wave) * 16 + l16;
            #pragma unroll
            for (int ks = 0; ks < 3; ++ks)
                wq[slot][ks] = ldb(ws + WSQ + c2 * 96 + ks * 32 + quad * 8);
        }
        // C-layout: col(channel) = l16, row(token) = quad*4 + r (+ mt*16)
        const int tt = nt * 4 + wave;
        const float bias = biasq[nt];
        if (nt < 3) {
            // q tiles: maxpool over the 4 M-tiles (pool groups are exactly mt)
            const int hd = tt / 6;
            const int d  = (tt % 6) * 16 + l16;
            #pragma unroll
            for (int r = 0; r < 4; ++r) {
                float m = fmaxf(fmaxf(acc[0][r], acc[1][r]), fmaxf(acc[2][r], acc[3][r])) + bias;
                qp_s[(hd * 16 + quad * 4 + r) * 104 + d] = f2bf(m);
            }
        } else {
            // K swizzled: col = ((d>>3)^(row&3))*8 + (d&7); row&3 == r here.
            const int tk = tt - 12;
            const int hd = tk / 6;
            const int dbh  = ((tk % 6) * 16) / 8 + (l16 >> 3);   // d>>3
            const int dlow = l16 & 7;
            #pragma unroll
            for (int mt = 0; mt < 4; ++mt)
                #pragma unroll
                for (int r = 0; r < 4; ++r)
                    k_s[hd * 6144 + (mt * 16 + quad * 4 + r) * 96 + ((dbh ^ r) << 3) + dlow]
                        = f2bf(acc[mt][r] + bias);
        }
    }
    __syncthreads();   // B3: qp/k ready

    // ---- phase 4: S^T = K @ qp^T (operand swap), per-lane softmax, P -> regs ----
    const int h   = wave >> 1;
    const int sub = wave & 1;
    bf16x8 qa[3];
    #pragma unroll
    for (int ks = 0; ks < 3; ++ks)
        qa[ks] = ldb(&qp_s[(h * 16 + l16) * 104 + ks * 32 + quad * 8]);
    // st[mt] C-layout: row = key (mt*16 + quad*4 + r), col = qrow (l16)
    f32x4 st[4];
    #pragma unroll
    for (int mt = 0; mt < 4; ++mt) st[mt] = (f32x4){0.f, 0.f, 0.f, 0.f};
    #pragma unroll
    for (int ks = 0; ks < 3; ++ks)
        #pragma unroll
        for (int mt = 0; mt < 4; ++mt) {
            bf16x8 kb = ldb(&k_s[h * 6144 + (mt * 16 + l16) * 96 + (((ks * 4 + quad) ^ (l16 & 3)) << 3)]);
            st[mt] = __builtin_amdgcn_mfma_f32_16x16x32_bf16(kb, qa[ks], st[mt], 0, 0, 0);
        }
    // softmax over the 16 per-lane values (all for qrow = l16) + cross-quad reduce
    const float cexp = 0.10206207261596576f * 1.4426950408889634f;  // 96^-0.5 * log2e
    float mx;
    {
        float m0 = fmaxf(fmaxf(st[0][0], st[0][1]), fmaxf(st[0][2], st[0][3]));
        float m1 = fmaxf(fmaxf(st[1][0], st[1][1]), fmaxf(st[1][2], st[1][3]));
        float m2 = fmaxf(fmaxf(st[2][0], st[2][1]), fmaxf(st[2][2], st[2][3]));
        float m3 = fmaxf(fmaxf(st[3][0], st[3][1]), fmaxf(st[3][2], st[3][3]));
        mx = fmaxf(fmaxf(m0, m1), fmaxf(m2, m3));
    }
    mx = fmaxf(mx, __shfl_xor(mx, 16));
    mx = fmaxf(mx, __shfl_xor(mx, 32));
    float e[4][4];
    #pragma unroll
    for (int mt = 0; mt < 4; ++mt)
        #pragma unroll
        for (int r = 0; r < 4; ++r)
            e[mt][r] = exp2f((st[mt][r] - mx) * cexp);
    float sum;
    {
        float s0 = (e[0][0] + e[0][1]) + (e[0][2] + e[0][3]);
        float s1 = (e[1][0] + e[1][1]) + (e[1][2] + e[1][3]);
        float s2 = (e[2][0] + e[2][1]) + (e[2][2] + e[2][3]);
        float s3 = (e[3][0] + e[3][1]) + (e[3][2] + e[3][3]);
        sum = (s0 + s1) + (s2 + s3);
    }
    sum += __shfl_xor(sum, 16);
    sum += __shfl_xor(sum, 32);
    const float rinv_l = 1.0f / sum;
    // redistribute rinv to O-epilogue layout (qrow = quad*4 + r)
    float rs[4];
    #pragma unroll
    for (int r = 0; r < 4; ++r)
        rs[r] = __shfl(rinv_l, (lane & 48) + quad * 4 + r);
    // assemble PV A-fragments in-register: pa[ks2] = P[qrow=l16][ks2*32+quad*8 ..+8]
    unsigned wlo[4], whi[4];
    #pragma unroll
    for (int mt = 0; mt < 4; ++mt) {
        wlo[mt] = (unsigned)f2bf(e[mt][0]) | ((unsigned)f2bf(e[mt][1]) << 16);
        whi[mt] = (unsigned)f2bf(e[mt][2]) | ((unsigned)f2bf(e[mt][3]) << 16);
    }
    bf16x8 pa[2];
    {
        const int srcA = ((quad & 1) * 2) * 16 + l16;   // first source quad-lane
        const int srcB = srcA + 16;                     // second source quad-lane
        const bool hiT = quad >= 2;                     // receiver tile = 2*ks2 + (quad>>1)
        #pragma unroll
        for (int ks2 = 0; ks2 < 2; ++ks2) {
            unsigned lo0a = __shfl(wlo[2 * ks2], srcA), lo0b = __shfl(wlo[2 * ks2 + 1], srcA);
            unsigned hi0a = __shfl(whi[2 * ks2], srcA), hi0b = __shfl(whi[2 * ks2 + 1], srcA);
            unsigned lo1a = __shfl(wlo[2 * ks2], srcB), lo1b = __shfl(wlo[2 * ks2 + 1], srcB);
            unsigned hi1a = __shfl(whi[2 * ks2], srcB), hi1b = __shfl(whi[2 * ks2 + 1], srcB);
            u32x4 W;
            W[0] = hiT ? lo0b : lo0a;
            W[1] = hiT ? hi0b : hi0a;
            W[2] = hiT ? lo1b : lo1a;
            W[3] = hiT ? hi1b : hi1a;
            pa[ks2] = __builtin_bit_cast(bf16x8, W);
        }
    }

    // ---- preload v-weight tiles 0,1 (2-deep rotation); hide under B4 wait ----
    bf16x8 wv[2][3];
    float  biasv[3];
    #pragma unroll
    for (int i = 0; i < 2; ++i) {
        const int c = 384 + (i * 4 + wave) * 16 + l16;
        #pragma unroll
        for (int ks = 0; ks < 3; ++ks)
            wv[i][ks] = ldb(ws + WSQ + c * 96 + ks * 32 + quad * 8);
    }
    #pragma unroll
    for (int i = 0; i < 3; ++i)
        biasv[i] = bf2f(ws[WSBQ + 384 + (i * 4 + wave) * 16 + l16]);
    __syncthreads();   // B4: all k reads done -> v may overwrite region 1

    // ---- phase 3b: v channels (afr still in regs); v swizzled [head][d][t] ----
    #pragma unroll
    for (int i = 0; i < 3; ++i) {
        const int slot = i & 1;   // compile-time after unroll
        f32x4 acc[4];
        #pragma unroll
        for (int mt = 0; mt < 4; ++mt) {
            acc[mt] = (f32x4){0.f, 0.f, 0.f, 0.f};
            #pragma unroll
            for (int ks = 0; ks < 3; ++ks)
                acc[mt] = __builtin_amdgcn_mfma_f32_16x16x32_bf16(afr[mt][ks], wv[slot][ks], acc[mt], 0, 0, 0);
        }
        if (i == 0) {   // refill slot 0 with tile 2
            const int c2 = 384 + (2 * 4 + wave) * 16 + l16;
            #pragma unroll
            for (int ks = 0; ks < 3; ++ks)
                wv[0][ks] = ldb(ws + WSQ + c2 * 96 + ks * 32 + quad * 8);
        }
        const int tv = i * 4 + wave;
        const int hd = tv / 6;
        const int d  = (tv % 6) * 16 + l16;
        const float bias = biasv[i];
        #pragma unroll
        for (int mt = 0; mt < 4; ++mt) {
            u16x4 pk;
            #pragma unroll
            for (int r = 0; r < 4; ++r) pk[r] = f2bf(acc[mt][r] + bias);
            const int tb = 2 * mt + (quad >> 1);     // t-block of t = mt*16 + quad*4
            *(u16x4*)&v_s[hd * 6144 + d * 64 + ((tb ^ (d & 7)) << 3) + (quad & 1) * 4] = pk;
        }
    }

    // ---- hoist proj weights/biases (afr/wv dead); land under B4b + PV ----
    const int cbase = wave * 48;
    bf16x8 wpr[3][6];
    float  biasp[3];
    #pragma unroll
    for (int i = 0; i < 3; ++i) {
        const int c = cbase + i * 16 + l16;
        #pragma unroll
        for (int ks = 0; ks < 6; ++ks)
            wpr[i][ks] = ldb(ws + WSP + c * 192 + ks * 32 + quad * 8);
        biasp[i] = bf2f(ws[WSBP + c]);
    }
    __syncthreads();   // B4b: v ready

    // ---- phase 5: O = P @ V (3 of 6 d-tiles per sub-wave), scale rows ----
    #pragma unroll
    for (int i = 0; i < 3; ++i) {
        const int n0 = (sub * 3 + i) * 16;
        f32x4 oacc = (f32x4){0.f, 0.f, 0.f, 0.f};
        #pragma unroll
        for (int ks2 = 0; ks2 < 2; ++ks2) {
            bf16x8 vb = ldb(&v_s[h * 6144 + (n0 + l16) * 64 + (((ks2 * 4 + quad) ^ (l16 & 7)) << 3)]);
            oacc = __builtin_amdgcn_mfma_f32_16x16x32_bf16(pa[ks2], vb, oacc, 0, 0, 0);
        }
        #pragma unroll
        for (int r = 0; r < 4; ++r)
            o_s[(quad * 4 + r) * 200 + h * 96 + n0 + l16] = f2bf(oacc[r] * rs[r]);
    }
    __syncthreads();   // B5: o ready

    // ---- phase 6: out = o @ w_proj^T + b_proj; wave owns 48 channels ----
    bf16x8 oa[6];
    #pragma unroll
    for (int ks = 0; ks < 6; ++ks)
        oa[ks] = ldb(&o_s[l16 * 200 + ks * 32 + quad * 8]);
    #pragma unroll
    for (int i = 0; i < 3; ++i) {
        const int c = cbase + i * 16 + l16;
        f32x4 acc = (f32x4){0.f, 0.f, 0.f, 0.f};
        #pragma unroll
        for (int ks = 0; ks < 6; ++ks)
            acc = __builtin_amdgcn_mfma_f32_16x16x32_bf16(oa[ks], wpr[i][ks], acc, 0, 0, 0);
        const float bias = biasp[i];
        #pragma unroll
        for (int r = 0; r < 4; ++r) {
            const int m = quad * 4 + r;          // out row = b*784 + m*49 + wi
            const size_t idx = ((size_t)(b * 784 + m * NW + wi)) * DOUT + c;
            if (f32m) ((float*)out)[idx] = acc[r] + bias;
            else      ((unsigned short*)out)[idx] = f2bf(acc[r] + bias);
        }
    }
}

extern "C" void kernel_launch(void* const* d_in, const int* in_sizes, int n_in,
                              void* d_out, int out_size, void* d_ws, size_t ws_size,
                              hipStream_t stream) {
    const void* x      = d_in[0];
    const void* w_qkv  = d_in[1];
    const void* b_qkv  = d_in[2];
    const void* w_proj = d_in[3];
    const void* b_proj = d_in[4];
    unsigned short* ws = (unsigned short*)d_ws;

    // Pre-kernel: convert weights/biases to bf16 into workspace (stream-ordered).
    dim3 gridc((WSTOT / 8 + 255) / 256), blockc(256);
    hipLaunchKernelGGL(conv_weights, gridc, blockc, 0, stream,
                       x, w_qkv, b_qkv, w_proj, b_proj, ws);

    dim3 grid(NTOK / 2), block(512);   // 1568 WGs x 2 parallel window-halves
    hipLaunchKernelGGL(mua_main, grid, block, 0, stream, x, ws, d_out);
}

// Round 11
// 173.463 us; speedup vs baseline: 1.5538x; 1.1336x over previous
//
#include <hip/hip_runtime.h>

// MaskUnitAttention fused kernel, MI355X gfx950.
// B=64, N=3136 (=64 tokens * 49 windows, window-fastest), DIM=96, DIM_OUT=192,
// HEADS=2, HEAD_DIM=96, Q_STRIDE=4, WINDOW_SIZE=16.
// v10: WAVE-COUNT HALVING. Fitting all clean rounds: dur ≈ waves/(~140/us)
// (v2/v4/v7/v9: 133-153 waves/us invariant across WG size/count; v9 refuted
// the WG-rate model). v10 restructures to 2 waves per window (128-thr block,
// one wave per head): S computed ONCE per head (v7 computed it redundantly in
// wave pairs), each wave owns 12 q+k tiles, 6 v tiles, full per-head attn,
// 6 proj tiles. Waves 12544 -> 6272 => launch floor ~45us. LDS layout/swizzles
// byte-identical to v7 (31.2KB, 5 blocks/CU cap). Rotating weight buffers
// sized to keep peak live ~120 VGPR; (128,3) caps at ~170 (no spill).

#define NW 49
#define NTOK 3136
#define DIM 96
#define DOUT 192

// ws layout (u16 element offsets)
#define WSQ 0
#define WSBQ 55296
#define WSP 55872
#define WSBP 92736
#define WSTOT 92928

typedef __bf16 bf16x8 __attribute__((ext_vector_type(8)));
typedef float f32x4 __attribute__((ext_vector_type(4)));
typedef unsigned short u16x8 __attribute__((ext_vector_type(8)));
typedef unsigned short u16x4 __attribute__((ext_vector_type(4)));
typedef unsigned int   u32x4 __attribute__((ext_vector_type(4)));

__device__ __forceinline__ unsigned short f2bf(float f) {
    return __builtin_bit_cast(unsigned short, (__bf16)f);   // RNE
}
__device__ __forceinline__ float bf2f(unsigned short h) {
    unsigned int u = ((unsigned int)h) << 16;
    return __builtin_bit_cast(float, u);
}

// Data sniff: x ~ N(0,1). bf16 data -> even-indexed u16s all have sane exponents.
// fp32 data -> even-indexed u16s are mantissa low-halves (uniform) -> ~16% sane.
__device__ __forceinline__ bool sniff_fp32(const unsigned short* x16) {
    int sane = 0;
    #pragma unroll
    for (int i = 0; i < 32; ++i) {
        unsigned e = ((unsigned)x16[2 * i] >> 7) & 0xFFu;
        sane += (e >= 100u && e <= 141u) ? 1 : 0;   // |v| in [2^-27, 2^14]
    }
    return sane < 24;
}

__device__ __forceinline__ bf16x8 ldb(const unsigned short* p) {
    return __builtin_bit_cast(bf16x8, *(const u16x8*)p);
}

// ---- pre-kernel: weights/biases -> bf16 in workspace (runs once, ~186 KB) ----
__global__ __launch_bounds__(256)
void conv_weights(const void* __restrict__ x,
                  const void* __restrict__ w_qkv, const void* __restrict__ b_qkv,
                  const void* __restrict__ w_proj, const void* __restrict__ b_proj,
                  unsigned short* __restrict__ ws)
{
    const bool f32m = sniff_fp32((const unsigned short*)x);
    int t = blockIdx.x * 256 + threadIdx.x;
    if (t >= WSTOT / 8) return;
    int off = t * 8;
    const void* src;
    int rel;
    if (off < WSBQ)      { src = w_qkv;  rel = off; }
    else if (off < WSP)  { src = b_qkv;  rel = off - WSBQ; }
    else if (off < WSBP) { src = w_proj; rel = off - WSP; }
    else                 { src = b_proj; rel = off - WSBP; }
    u16x8 v;
    if (f32m) {
        const float* p = (const float*)src + rel;
        f32x4 a = *(const f32x4*)p;
        f32x4 bb = *(const f32x4*)(p + 4);
        v[0] = f2bf(a[0]);  v[1] = f2bf(a[1]);  v[2] = f2bf(a[2]);  v[3] = f2bf(a[3]);
        v[4] = f2bf(bb[0]); v[5] = f2bf(bb[1]); v[6] = f2bf(bb[2]); v[7] = f2bf(bb[3]);
    } else {
        v = *(const u16x8*)((const unsigned short*)src + rel);
    }
    *(u16x8*)(ws + off) = v;
}

// ---- main fused kernel: one 128-thread block (2 waves) per (b, window);
//      wave == head ----
__global__ __launch_bounds__(128, 3)
void mua_main(const void* __restrict__ x,
              const unsigned short* __restrict__ ws,
              void* __restrict__ out)
{
    const int bid = blockIdx.x;
    const int b   = bid / NW;
    const int wi  = bid - b * NW;
    const int tid  = threadIdx.x;
    const int h    = tid >> 6;          // wave index == head
    const int lane = tid & 63;
    const int quad = lane >> 4;
    const int l16  = lane & 15;

    // 31232 B LDS -> 5 blocks/CU cap. Region 1 (u16 [0,12288)) time-shared:
    //   x_s [64][104]              (dead after B2)
    //   k_s [2][64][96] swizzled   (written after B2, dead after B4)
    //   v_s [2][96][64] swizzled   (written after B4)
    // qp_s [2][16][104] @12288 (o_s [16][200]=3200 aliases; qp dead after qa reads)
    __shared__ __attribute__((aligned(16))) unsigned short lds[15616];
    unsigned short* x_s  = lds;
    unsigned short* k_s  = lds;
    unsigned short* v_s  = lds;
    unsigned short* qp_s = lds + 12288;
    unsigned short* o_s  = lds + 12288;

    // ---- preload wq tiles 0..2 (3-deep rotation, 36 regs) + all biases ----
    // Tile tt = nt*2 + h: nt 0..5 -> q tiles (tt 0..11), nt 6..11 -> k (12..23).
    bf16x8 wq[3][3];
    float  biasq[12];
    #pragma unroll
    for (int nt = 0; nt < 3; ++nt) {
        const int c = (nt * 2 + h) * 16 + l16;
        #pragma unroll
        for (int ks = 0; ks < 3; ++ks)
            wq[nt][ks] = ldb(ws + WSQ + c * 96 + ks * 32 + quad * 8);
    }
    #pragma unroll
    for (int nt = 0; nt < 12; ++nt)
        biasq[nt] = bf2f(ws[WSBQ + (nt * 2 + h) * 16 + l16]);

    const bool f32m = sniff_fp32((const unsigned short*)x);

    // ---- phase 1: stage x tile (64 rows x 96, rows strided by 49*96) ----
    {
        const size_t xoff = ((size_t)b * NTOK + wi) * DIM;
        if (f32m) {
            #pragma unroll
            for (int i = 0; i < 6; ++i) {
                int chunk = tid + i * 128;          // 768 = 64 rows * 12 chunks
                int row = chunk / 12;
                int c16 = chunk - row * 12;
                const float* p = (const float*)x + xoff + (size_t)row * (NW * DIM) + c16 * 8;
                f32x4 a = *(const f32x4*)p;
                f32x4 bb = *(const f32x4*)(p + 4);
                u16x8 r;
                r[0] = f2bf(a[0]);  r[1] = f2bf(a[1]);  r[2] = f2bf(a[2]);  r[3] = f2bf(a[3]);
                r[4] = f2bf(bb[0]); r[5] = f2bf(bb[1]); r[6] = f2bf(bb[2]); r[7] = f2bf(bb[3]);
                *(u16x8*)&x_s[row * 104 + c16 * 8] = r;
            }
        } else {
            #pragma unroll
            for (int i = 0; i < 6; ++i) {
                int chunk = tid + i * 128;
                int row = chunk / 12;
                int c16 = chunk - row * 12;
                const unsigned short* p = (const unsigned short*)x + xoff + (size_t)row * (NW * DIM) + c16 * 8;
                *(u16x8*)&x_s[row * 104 + c16 * 8] = *(const u16x8*)p;
            }
        }
    }
    __syncthreads();   // B1: x staged (also drains preloaded wq tiles)

    // ---- phase 2: A-fragments of x into registers (live until v-GEMM) ----
    bf16x8 afr[4][3];
    #pragma unroll
    for (int mt = 0; mt < 4; ++mt)
        #pragma unroll
        for (int ks = 0; ks < 3; ++ks)
            afr[mt][ks] = ldb(&x_s[(mt * 16 + l16) * 104 + ks * 32 + quad * 8]);
    __syncthreads();   // B2: x region free -> k may overwrite

    // ---- phase 3a: q+k channels (12 tiles/wave); slot nt%3 refilled with nt+3 ----
    #pragma unroll
    for (int nt = 0; nt < 12; ++nt) {
        const int slot = nt % 3;   // compile-time after unroll
        f32x4 acc[4];
        #pragma unroll
        for (int mt = 0; mt < 4; ++mt) {
            acc[mt] = (f32x4){0.f, 0.f, 0.f, 0.f};
            #pragma unroll
            for (int ks = 0; ks < 3; ++ks)
                acc[mt] = __builtin_amdgcn_mfma_f32_16x16x32_bf16(afr[mt][ks], wq[slot][ks], acc[mt], 0, 0, 0);
        }
        if (nt < 9) {   // refill slot with tile nt+3 (WAR on slot orders after MFMAs)
            const int c2 = ((nt + 3) * 2 + h) * 16 + l16;
            #pragma unroll
            for (int ks = 0; ks < 3; ++ks)
                wq[slot][ks] = ldb(ws + WSQ + c2 * 96 + ks * 32 + quad * 8);
        }
        // C-layout: col(channel) = l16, row(token) = quad*4 + r (+ mt*16)
        const int tt = nt * 2 + h;
        const float bias = biasq[nt];
        if (nt < 6) {
            // q tiles: maxpool over the 4 M-tiles (pool groups are exactly mt)
            const int hd = tt / 6;
            const int d  = (tt % 6) * 16 + l16;
            #pragma unroll
            for (int r = 0; r < 4; ++r) {
                float m = fmaxf(fmaxf(acc[0][r], acc[1][r]), fmaxf(acc[2][r], acc[3][r])) + bias;
                qp_s[(hd * 16 + quad * 4 + r) * 104 + d] = f2bf(m);
            }
        } else {
            // K swizzled: col = ((d>>3)^(row&3))*8 + (d&7); row&3 == r here.
            const int tk = tt - 12;
            const int hd = tk / 6;
            const int dbh  = ((tk % 6) * 16) / 8 + (l16 >> 3);   // d>>3
            const int dlow = l16 & 7;
            #pragma unroll
            for (int mt = 0; mt < 4; ++mt)
                #pragma unroll
                for (int r = 0; r < 4; ++r)
                    k_s[hd * 6144 + (mt * 16 + quad * 4 + r) * 96 + ((dbh ^ r) << 3) + dlow]
                        = f2bf(acc[mt][r] + bias);
        }
    }
    __syncthreads();   // B3: qp/k ready

    // ---- phase 4: S^T = K @ qp^T (operand swap), per-lane softmax, P -> regs.
    //      Wave h computes head h ONCE (no redundant pair). ----
    bf16x8 qa[3];
    #pragma unroll
    for (int ks = 0; ks < 3; ++ks)
        qa[ks] = ldb(&qp_s[(h * 16 + l16) * 104 + ks * 32 + quad * 8]);
    // st[mt] C-layout: row = key (mt*16 + quad*4 + r), col = qrow (l16)
    f32x4 st[4];
    #pragma unroll
    for (int mt = 0; mt < 4; ++mt) st[mt] = (f32x4){0.f, 0.f, 0.f, 0.f};
    #pragma unroll
    for (int ks = 0; ks < 3; ++ks)
        #pragma unroll
        for (int mt = 0; mt < 4; ++mt) {
            bf16x8 kb = ldb(&k_s[h * 6144 + (mt * 16 + l16) * 96 + (((ks * 4 + quad) ^ (l16 & 3)) << 3)]);
            st[mt] = __builtin_amdgcn_mfma_f32_16x16x32_bf16(kb, qa[ks], st[mt], 0, 0, 0);
        }
    // softmax over the 16 per-lane values (all for qrow = l16) + cross-quad reduce
    const float cexp = 0.10206207261596576f * 1.4426950408889634f;  // 96^-0.5 * log2e
    float mx;
    {
        float m0 = fmaxf(fmaxf(st[0][0], st[0][1]), fmaxf(st[0][2], st[0][3]));
        float m1 = fmaxf(fmaxf(st[1][0], st[1][1]), fmaxf(st[1][2], st[1][3]));
        float m2 = fmaxf(fmaxf(st[2][0], st[2][1]), fmaxf(st[2][2], st[2][3]));
        float m3 = fmaxf(fmaxf(st[3][0], st[3][1]), fmaxf(st[3][2], st[3][3]));
        mx = fmaxf(fmaxf(m0, m1), fmaxf(m2, m3));
    }
    mx = fmaxf(mx, __shfl_xor(mx, 16));
    mx = fmaxf(mx, __shfl_xor(mx, 32));
    float e[4][4];
    #pragma unroll
    for (int mt = 0; mt < 4; ++mt)
        #pragma unroll
        for (int r = 0; r < 4; ++r)
            e[mt][r] = exp2f((st[mt][r] - mx) * cexp);
    float sum;
    {
        float s0 = (e[0][0] + e[0][1]) + (e[0][2] + e[0][3]);
        float s1 = (e[1][0] + e[1][1]) + (e[1][2] + e[1][3]);
        float s2 = (e[2][0] + e[2][1]) + (e[2][2] + e[2][3]);
        float s3 = (e[3][0] + e[3][1]) + (e[3][2] + e[3][3]);
        sum = (s0 + s1) + (s2 + s3);
    }
    sum += __shfl_xor(sum, 16);
    sum += __shfl_xor(sum, 32);
    const float rinv_l = 1.0f / sum;
    // redistribute rinv to O-epilogue layout (qrow = quad*4 + r)
    float rs[4];
    #pragma unroll
    for (int r = 0; r < 4; ++r)
        rs[r] = __shfl(rinv_l, (lane & 48) + quad * 4 + r);
    // assemble PV A-fragments in-register: pa[ks2] = P[qrow=l16][ks2*32+quad*8 ..+8]
    unsigned wlo[4], whi[4];
    #pragma unroll
    for (int mt = 0; mt < 4; ++mt) {
        wlo[mt] = (unsigned)f2bf(e[mt][0]) | ((unsigned)f2bf(e[mt][1]) << 16);
        whi[mt] = (unsigned)f2bf(e[mt][2]) | ((unsigned)f2bf(e[mt][3]) << 16);
    }
    bf16x8 pa[2];
    {
        const int srcA = ((quad & 1) * 2) * 16 + l16;   // first source quad-lane
        const int srcB = srcA + 16;                     // second source quad-lane
        const bool hiT = quad >= 2;                     // receiver tile = 2*ks2 + (quad>>1)
        #pragma unroll
        for (int ks2 = 0; ks2 < 2; ++ks2) {
            unsigned lo0a = __shfl(wlo[2 * ks2], srcA), lo0b = __shfl(wlo[2 * ks2 + 1], srcA);
            unsigned hi0a = __shfl(whi[2 * ks2], srcA), hi0b = __shfl(whi[2 * ks2 + 1], srcA);
            unsigned lo1a = __shfl(wlo[2 * ks2], srcB), lo1b = __shfl(wlo[2 * ks2 + 1], srcB);
            unsigned hi1a = __shfl(whi[2 * ks2], srcB), hi1b = __shfl(whi[2 * ks2 + 1], srcB);
            u32x4 W;
            W[0] = hiT ? lo0b : lo0a;
            W[1] = hiT ? hi0b : hi0a;
            W[2] = hiT ? lo1b : lo1a;
            W[3] = hiT ? hi1b : hi1a;
            pa[ks2] = __builtin_bit_cast(bf16x8, W);
        }
    }

    // ---- preload v-weight tiles 0,1 (2-deep rotation); hide under B4 wait ----
    bf16x8 wv[2][3];
    float  biasv[6];
    #pragma unroll
    for (int i = 0; i < 2; ++i) {
        const int c = 384 + (i * 2 + h) * 16 + l16;
        #pragma unroll
        for (int ks = 0; ks < 3; ++ks)
            wv[i][ks] = ldb(ws + WSQ + c * 96 + ks * 32 + quad * 8);
    }
    #pragma unroll
    for (int i = 0; i < 6; ++i)
        biasv[i] = bf2f(ws[WSBQ + 384 + (i * 2 + h) * 16 + l16]);
    __syncthreads();   // B4: all k reads done -> v may overwrite region 1

    // ---- phase 3b: v channels (6 tiles/wave, afr still in regs); v swizzled ----
    #pragma unroll
    for (int i = 0; i < 6; ++i) {
        const int slot = i & 1;   // compile-time after unroll
        f32x4 acc[4];
        #pragma unroll
        for (int mt = 0; mt < 4; ++mt) {
            acc[mt] = (f32x4){0.f, 0.f, 0.f, 0.f};
            #pragma unroll
            for (int ks = 0; ks < 3; ++ks)
                acc[mt] = __builtin_amdgcn_mfma_f32_16x16x32_bf16(afr[mt][ks], wv[slot][ks], acc[mt], 0, 0, 0);
        }
        if (i < 4) {   // refill slot with tile i+2
            const int c2 = 384 + ((i + 2) * 2 + h) * 16 + l16;
            #pragma unroll
            for (int ks = 0; ks < 3; ++ks)
                wv[slot][ks] = ldb(ws + WSQ + c2 * 96 + ks * 32 + quad * 8);
        }
        const int tv = i * 2 + h;
        const int hd = tv / 6;
        const int d  = (tv % 6) * 16 + l16;
        const float bias = biasv[i];
        #pragma unroll
        for (int mt = 0; mt < 4; ++mt) {
            u16x4 pk;
            #pragma unroll
            for (int r = 0; r < 4; ++r) pk[r] = f2bf(acc[mt][r] + bias);
            const int tb = 2 * mt + (quad >> 1);     // t-block of t = mt*16 + quad*4
            *(u16x4*)&v_s[hd * 6144 + d * 64 + ((tb ^ (d & 7)) << 3) + (quad & 1) * 4] = pk;
        }
    }

    // ---- preload proj tiles 0,1 (2-deep rotation; afr/wv dead) + biases ----
    const int cbase = h * 96;
    bf16x8 wpr[2][6];
    float  biasp[6];
    #pragma unroll
    for (int i = 0; i < 2; ++i) {
        const int c = cbase + i * 16 + l16;
        #pragma unroll
        for (int ks = 0; ks < 6; ++ks)
            wpr[i][ks] = ldb(ws + WSP + c * 192 + ks * 32 + quad * 8);
    }
    #pragma unroll
    for (int i = 0; i < 6; ++i)
        biasp[i] = bf2f(ws[WSBP + cbase + i * 16 + l16]);
    __syncthreads();   // B4b: v ready

    // ---- phase 5: O = P @ V (all 6 d-tiles of head h), scale rows by rinv ----
    #pragma unroll
    for (int i = 0; i < 6; ++i) {
        const int n0 = i * 16;
        f32x4 oacc = (f32x4){0.f, 0.f, 0.f, 0.f};
        #pragma unroll
        for (int ks2 = 0; ks2 < 2; ++ks2) {
            bf16x8 vb = ldb(&v_s[h * 6144 + (n0 + l16) * 64 + (((ks2 * 4 + quad) ^ (l16 & 7)) << 3)]);
            oacc = __builtin_amdgcn_mfma_f32_16x16x32_bf16(pa[ks2], vb, oacc, 0, 0, 0);
        }
        #pragma unroll
        for (int r = 0; r < 4; ++r)
            o_s[(quad * 4 + r) * 200 + h * 96 + n0 + l16] = f2bf(oacc[r] * rs[r]);
    }
    __syncthreads();   // B5: o ready

    // ---- phase 6: out = o @ w_proj^T + b_proj; wave owns 96 of 192 channels;
    //      wpr slot i&1 refilled with tile i+2 during the loop ----
    bf16x8 oa[6];
    #pragma unroll
    for (int ks = 0; ks < 6; ++ks)
        oa[ks] = ldb(&o_s[l16 * 200 + ks * 32 + quad * 8]);
    #pragma unroll
    for (int i = 0; i < 6; ++i) {
        const int slot = i & 1;   // compile-time after unroll
        const int c = cbase + i * 16 + l16;
        f32x4 acc = (f32x4){0.f, 0.f, 0.f, 0.f};
        #pragma unroll
        for (int ks = 0; ks < 6; ++ks)
            acc = __builtin_amdgcn_mfma_f32_16x16x32_bf16(oa[ks], wpr[slot][ks], acc, 0, 0, 0);
        if (i < 4) {   // refill slot with tile i+2
            const int c2 = cbase + (i + 2) * 16 + l16;
            #pragma unroll
            for (int ks = 0; ks < 6; ++ks)
                wpr[slot][ks] = ldb(ws + WSP + c2 * 192 + ks * 32 + quad * 8);
        }
        const float bias = biasp[i];
        #pragma unroll
        for (int r = 0; r < 4; ++r) {
            const int m = quad * 4 + r;          // out row = b*784 + m*49 + wi
            const size_t idx = ((size_t)(b * 784 + m * NW + wi)) * DOUT + c;
            if (f32m) ((float*)out)[idx] = acc[r] + bias;
            else      ((unsigned short*)out)[idx] = f2bf(acc[r] + bias);
        }
    }
}

extern "C" void kernel_launch(void* const* d_in, const int* in_sizes, int n_in,
                              void* d_out, int out_size, void* d_ws, size_t ws_size,
                              hipStream_t stream) {
    const void* x      = d_in[0];
    const void* w_qkv  = d_in[1];
    const void* b_qkv  = d_in[2];
    const void* w_proj = d_in[3];
    const void* b_proj = d_in[4];
    unsigned short* ws = (unsigned short*)d_ws;

    // Pre-kernel: convert weights/biases to bf16 into workspace (stream-ordered).
    dim3 gridc((WSTOT / 8 + 255) / 256), blockc(256);
    hipLaunchKernelGGL(conv_weights, gridc, blockc, 0, stream,
                       x, w_qkv, b_qkv, w_proj, b_proj, ws);

    dim3 grid(NTOK), block(128);   // 3136 blocks x 2 waves (one per head)
    hipLaunchKernelGGL(mua_main, grid, block, 0, stream, x, ws, d_out);
}